// Round 1
// baseline (931.312 us; speedup 1.0000x reference)
//
#include <hip/hip_runtime.h>
#include <cstdint>
#include <cstddef>

// ---------- types ----------
typedef __bf16 bf16x8 __attribute__((ext_vector_type(8)));
typedef float  f32x4  __attribute__((ext_vector_type(4)));

__device__ __forceinline__ unsigned short f2bf(float f) {
  unsigned int u = __float_as_uint(f);
  u += 0x7FFF + ((u >> 16) & 1);       // round-to-nearest-even
  return (unsigned short)(u >> 16);
}

#define SEQ 2048
#define DMODEL 2048
#define NH 16
#define HD 128
#define NB 2
#define NP 10
#define MAUG 4106   // NB*SEQ + NP
#define SCALE 0.08838834764831845f  // 1/sqrt(128)

// ---------- 1. RoPE tables (double precision) ----------
__global__ void k_tables(float* __restrict__ cost, float* __restrict__ sint) {
  int idx = blockIdx.x * 256 + threadIdx.x;   // SEQ*64
  if (idx >= SEQ * 64) return;
  int s = idx >> 6, i = idx & 63;
  double invf = exp(-((double)(2 * i) / 128.0) * log(10000.0));
  double a = (double)s * invf;
  float c = (float)cos(a), sn = (float)sin(a);
  cost[s * HD + i] = c;  cost[s * HD + 64 + i] = c;
  sint[s * HD + i] = sn; sint[s * HD + 64 + i] = sn;
}

// ---------- 2. weight transpose + cast: W[k][n] fp32 -> Wt[n][k] bf16 ----------
__global__ __launch_bounds__(256) void k_wt(const float* __restrict__ W0,
                                            const float* __restrict__ W1,
                                            const float* __restrict__ W2,
                                            const float* __restrict__ W3,
                                            unsigned short* __restrict__ out) {
  __shared__ float tile[32][33];
  const float* W = (blockIdx.z == 0) ? W0 : (blockIdx.z == 1) ? W1 : (blockIdx.z == 2) ? W2 : W3;
  unsigned short* o = out + (size_t)blockIdx.z * DMODEL * DMODEL;
  int bx = blockIdx.x * 32;  // k base
  int by = blockIdx.y * 32;  // n base
  int tx = threadIdx.x & 31, ty = threadIdx.x >> 5;
  #pragma unroll
  for (int j = 0; j < 32; j += 8)
    tile[ty + j][tx] = W[(size_t)(bx + ty + j) * DMODEL + by + tx];
  __syncthreads();
  #pragma unroll
  for (int j = 0; j < 32; j += 8)
    o[(size_t)(by + ty + j) * DMODEL + bx + tx] = f2bf(tile[tx][ty + j]);
}

// ---------- 3. X augmented with adapter rows, cast to bf16 ----------
__global__ void k_xaug(const float* __restrict__ X, const float* __restrict__ Aq,
                       unsigned short* __restrict__ xaug) {
  size_t idx = (size_t)blockIdx.x * 256 + threadIdx.x;
  if (idx >= (size_t)MAUG * DMODEL) return;
  size_t row = idx >> 11;
  int col = (int)(idx & 2047);
  float v = (row < (size_t)NB * SEQ) ? X[idx] : Aq[(row - NB * SEQ) * DMODEL + col];
  xaug[idx] = f2bf(v);
}

// ---------- 4. bf16 MFMA GEMM: C[z] = A @ Wt[z]^T ----------
__global__ __launch_bounds__(256) void k_gemm(const unsigned short* __restrict__ A,
                                              const unsigned short* __restrict__ Bt,
                                              float* __restrict__ C,
                                              int M, size_t c_stride_mat) {
  __shared__ unsigned short As[128 * 32];
  __shared__ unsigned short Bs[128 * 32];
  const int t = threadIdx.x;
  const int lane = t & 63, w = t >> 6;
  const int lr = lane & 15, quad = lane >> 4;
  const int wm = (w & 1) * 64, wn = (w >> 1) * 64;
  const int m0 = blockIdx.y * 128, n0 = blockIdx.x * 128;
  const unsigned short* Btz = Bt + (size_t)blockIdx.z * DMODEL * DMODEL;
  float* Cz = C + (size_t)blockIdx.z * c_stride_mat;

  f32x4 acc[4][4];
  #pragma unroll
  for (int i = 0; i < 4; i++)
    #pragma unroll
    for (int j = 0; j < 4; j++) acc[i][j] = (f32x4){0.f, 0.f, 0.f, 0.f};

  for (int kt = 0; kt < DMODEL / 32; kt++) {
    const int k0 = kt * 32;
    #pragma unroll
    for (int i = 0; i < 2; i++) {
      int idx = t + i * 256;
      int row = idx >> 2, ch = idx & 3;
      int gm = m0 + row;
      uint4 va = {0u, 0u, 0u, 0u};
      if (gm < M) va = *(const uint4*)&A[(size_t)gm * DMODEL + k0 + ch * 8];
      *(uint4*)&As[row * 32 + ch * 8] = va;
      uint4 vb = *(const uint4*)&Btz[(size_t)(n0 + row) * DMODEL + k0 + ch * 8];
      *(uint4*)&Bs[row * 32 + ch * 8] = vb;
    }
    __syncthreads();
    bf16x8 af[4], bfv[4];
    #pragma unroll
    for (int mt = 0; mt < 4; mt++) af[mt] = *(const bf16x8*)&As[(wm + mt * 16 + lr) * 32 + quad * 8];
    #pragma unroll
    for (int nt = 0; nt < 4; nt++) bfv[nt] = *(const bf16x8*)&Bs[(wn + nt * 16 + lr) * 32 + quad * 8];
    #pragma unroll
    for (int mt = 0; mt < 4; mt++)
      #pragma unroll
      for (int nt = 0; nt < 4; nt++)
        acc[mt][nt] = __builtin_amdgcn_mfma_f32_16x16x32_bf16(af[mt], bfv[nt], acc[mt][nt], 0, 0, 0);
    __syncthreads();
  }
  #pragma unroll
  for (int mt = 0; mt < 4; mt++) {
    #pragma unroll
    for (int r = 0; r < 4; r++) {
      int row = m0 + wm + mt * 16 + quad * 4 + r;
      if (row < M) {
        #pragma unroll
        for (int nt = 0; nt < 4; nt++)
          Cz[(size_t)row * DMODEL + n0 + wn + nt * 16 + lr] = acc[mt][nt][r];
      }
    }
  }
}

// ---------- 5. RoPE + cast; V transposed to [b,h,d,s]; adapter rows split off ----------
__global__ __launch_bounds__(256) void k_rope(const float* __restrict__ Qf, const float* __restrict__ Kf,
                                              const float* __restrict__ Vf,
                                              const float* __restrict__ cost, const float* __restrict__ sint,
                                              unsigned short* __restrict__ Qb, unsigned short* __restrict__ Kb,
                                              unsigned short* __restrict__ Vt,
                                              unsigned short* __restrict__ AKb, unsigned short* __restrict__ AVb) {
  int row = blockIdx.x;  // 0..MAUG-1
  int t = threadIdx.x;
  if (row < NB * SEQ) {
    int s = row & (SEQ - 1);
    int b = row >> 11;
    #pragma unroll
    for (int i = 0; i < 8; i++) {
      int c = t + i * 256;
      int d = c & (HD - 1), h = c >> 7;
      float cv = cost[s * HD + d], sv = sint[s * HD + d];
      size_t off = (size_t)row * DMODEL + c;
      size_t off2 = (size_t)row * DMODEL + ((d < 64) ? (c + 64) : (c - 64));
      float q = Qf[off], k = Kf[off];
      float qr = (d < 64) ? -Qf[off2] : Qf[off2];
      float kr = (d < 64) ? -Kf[off2] : Kf[off2];
      Qb[off] = f2bf(q * cv + qr * sv);
      Kb[off] = f2bf(k * cv + kr * sv);
      Vt[((size_t)(b * NH + h) * HD + d) * SEQ + s] = f2bf(Vf[off]);
    }
  } else {
    int p = row - NB * SEQ;
    #pragma unroll
    for (int i = 0; i < 8; i++) {
      int c = t + i * 256;
      size_t off = (size_t)row * DMODEL + c;
      AKb[p * DMODEL + c] = f2bf(Kf[off]);
      AVb[p * DMODEL + c] = f2bf(Vf[off]);
    }
  }
}

// ---------- 6. flash attention + fused adapter ----------
__global__ __launch_bounds__(256) void k_flash(const unsigned short* __restrict__ Qb,
                                               const unsigned short* __restrict__ Kb,
                                               const unsigned short* __restrict__ Vt,
                                               const unsigned short* __restrict__ AKb,
                                               const unsigned short* __restrict__ AVb,
                                               const float* __restrict__ gate,
                                               float* __restrict__ Out) {
  const int qt = blockIdx.x;   // 0..31 (64-row q tiles)
  const int h  = blockIdx.y;
  const int b  = blockIdx.z;
  const int t = threadIdx.x, w = t >> 6, lane = t & 63;
  const int lr = lane & 15, quad = lane >> 4;

  __shared__ unsigned short Ks[64 * 128];   // [k-row][d]
  __shared__ unsigned short Vs[128 * 64];   // [d][k-row] (from Vt)
  __shared__ unsigned short Ps[4][16 * 64]; // per-wave P buffer
  __shared__ unsigned short AKs[16 * 128];  // adapter K [p(pad16)][d]
  __shared__ unsigned short AVs[128 * 32];  // adapter V [d][p(pad32)]

  // adapter tiles (once)
  for (int i = t; i < 16 * 128; i += 256) {
    int p = i >> 7, d = i & 127;
    AKs[i] = (p < NP) ? AKb[(size_t)p * DMODEL + h * HD + d] : (unsigned short)0;
  }
  for (int i = t; i < 128 * 32; i += 256) {
    int d = i >> 5, p = i & 31;
    AVs[i] = (p < NP) ? AVb[(size_t)p * DMODEL + h * HD + d] : (unsigned short)0;
  }

  // Q fragments (A-layout), persistent in registers
  const int qrow = qt * 64 + w * 16 + lr;
  bf16x8 qf[4];
  #pragma unroll
  for (int kk = 0; kk < 4; kk++)
    qf[kk] = *(const bf16x8*)&Qb[((size_t)(b * SEQ + qrow)) * DMODEL + h * HD + kk * 32 + quad * 8];

  f32x4 o[8];
  #pragma unroll
  for (int nt = 0; nt < 8; nt++) o[nt] = (f32x4){0.f, 0.f, 0.f, 0.f};
  float m_i[4], l_i[4];
  #pragma unroll
  for (int r = 0; r < 4; r++) { m_i[r] = -__builtin_inff(); l_i[r] = 0.f; }

  for (int kt = 0; kt <= qt; kt++) {
    __syncthreads();   // previous iteration's LDS reads done
    for (int i = t; i < 1024; i += 256) {        // K tile 64x128 (16B chunks)
      int row = i >> 4, ch = i & 15;
      *(uint4*)&Ks[row * 128 + ch * 8] =
        *(const uint4*)&Kb[((size_t)(b * SEQ + kt * 64 + row)) * DMODEL + h * HD + ch * 8];
    }
    for (int i = t; i < 1024; i += 256) {        // V^T tile 128x64
      int d = i >> 3, ch = i & 7;
      *(uint4*)&Vs[d * 64 + ch * 8] =
        *(const uint4*)&Vt[((size_t)((b * NH + h) * HD + d)) * SEQ + kt * 64 + ch * 8];
    }
    __syncthreads();

    // S = Q K^T  (C-layout: row=quad*4+r, col=nt*16+lr)
    f32x4 s4[4];
    #pragma unroll
    for (int nt = 0; nt < 4; nt++) {
      f32x4 a = (f32x4){0.f, 0.f, 0.f, 0.f};
      #pragma unroll
      for (int kk = 0; kk < 4; kk++) {
        bf16x8 bv = *(const bf16x8*)&Ks[(nt * 16 + lr) * 128 + kk * 32 + quad * 8];
        a = __builtin_amdgcn_mfma_f32_16x16x32_bf16(qf[kk], bv, a, 0, 0, 0);
      }
      s4[nt] = a * SCALE;
    }
    if (kt == qt) {  // causal mask within diagonal 64-tile
      #pragma unroll
      for (int nt = 0; nt < 4; nt++) {
        int col = nt * 16 + lr;
        #pragma unroll
        for (int r = 0; r < 4; r++)
          if (col > w * 16 + quad * 4 + r) s4[nt][r] = -__builtin_inff();
      }
    }
    // online softmax (16-lane butterfly per quad-group = one score row)
    float alpha[4];
    #pragma unroll
    for (int r = 0; r < 4; r++) {
      float tm = fmaxf(fmaxf(s4[0][r], s4[1][r]), fmaxf(s4[2][r], s4[3][r]));
      #pragma unroll
      for (int off = 1; off < 16; off <<= 1) tm = fmaxf(tm, __shfl_xor(tm, off, 64));
      float mnew = fmaxf(m_i[r], tm);
      float p0 = __expf(s4[0][r] - mnew), p1 = __expf(s4[1][r] - mnew);
      float p2 = __expf(s4[2][r] - mnew), p3 = __expf(s4[3][r] - mnew);
      s4[0][r] = p0; s4[1][r] = p1; s4[2][r] = p2; s4[3][r] = p3;
      float sum = p0 + p1 + p2 + p3;
      #pragma unroll
      for (int off = 1; off < 16; off <<= 1) sum += __shfl_xor(sum, off, 64);
      alpha[r] = __expf(m_i[r] - mnew);
      l_i[r] = alpha[r] * l_i[r] + sum;
      m_i[r] = mnew;
    }
    #pragma unroll
    for (int nt = 0; nt < 4; nt++)
      #pragma unroll
      for (int r = 0; r < 4; r++)
        Ps[w][(quad * 4 + r) * 64 + nt * 16 + lr] = f2bf(s4[nt][r]);
    #pragma unroll
    for (int nt = 0; nt < 8; nt++)
      #pragma unroll
      for (int r = 0; r < 4; r++) o[nt][r] *= alpha[r];
    __syncthreads();   // P visible (and paces waves)
    // O += P V  (P via A-layout from LDS)
    #pragma unroll
    for (int kk2 = 0; kk2 < 2; kk2++) {
      bf16x8 af = *(const bf16x8*)&Ps[w][lr * 64 + kk2 * 32 + quad * 8];
      #pragma unroll
      for (int nt = 0; nt < 8; nt++) {
        bf16x8 bv = *(const bf16x8*)&Vs[(nt * 16 + lr) * 64 + kk2 * 32 + quad * 8];
        o[nt] = __builtin_amdgcn_mfma_f32_16x16x32_bf16(af, bv, o[nt], 0, 0, 0);
      }
    }
  }
  __syncthreads();

  // ---- adapter: separate 10-way softmax, fused here ----
  f32x4 as4 = (f32x4){0.f, 0.f, 0.f, 0.f};
  #pragma unroll
  for (int kk = 0; kk < 4; kk++) {
    bf16x8 bv = *(const bf16x8*)&AKs[lr * 128 + kk * 32 + quad * 8];
    as4 = __builtin_amdgcn_mfma_f32_16x16x32_bf16(qf[kk], bv, as4, 0, 0, 0);
  }
  as4 = as4 * SCALE;
  if (lr >= NP) {
    #pragma unroll
    for (int r = 0; r < 4; r++) as4[r] = -__builtin_inff();
  }
  float al[4];
  #pragma unroll
  for (int r = 0; r < 4; r++) {
    float tm = as4[r];
    #pragma unroll
    for (int off = 1; off < 16; off <<= 1) tm = fmaxf(tm, __shfl_xor(tm, off, 64));
    float p = __expf(as4[r] - tm);     // -inf lanes -> 0
    as4[r] = p;
    float sum = p;
    #pragma unroll
    for (int off = 1; off < 16; off <<= 1) sum += __shfl_xor(sum, off, 64);
    al[r] = sum;
  }
  #pragma unroll
  for (int r = 0; r < 4; r++) {
    Ps[w][(quad * 4 + r) * 64 + lr] = f2bf(as4[r]);
    Ps[w][(quad * 4 + r) * 64 + 16 + lr] = 0;
  }
  __syncthreads();
  f32x4 pa[8];
  {
    bf16x8 af = *(const bf16x8*)&Ps[w][lr * 64 + quad * 8];
    #pragma unroll
    for (int nt = 0; nt < 8; nt++) {
      bf16x8 bv = *(const bf16x8*)&AVs[(nt * 16 + lr) * 32 + quad * 8];
      pa[nt] = __builtin_amdgcn_mfma_f32_16x16x32_bf16(af, bv, (f32x4){0.f, 0.f, 0.f, 0.f}, 0, 0, 0);
    }
  }
  const float g = gate[h];
  #pragma unroll
  for (int r = 0; r < 4; r++) {
    float invl = 1.0f / l_i[r];
    float invla = g / al[r];
    int srow = qt * 64 + w * 16 + quad * 4 + r;
    size_t base = ((size_t)(b * SEQ + srow)) * DMODEL + h * HD;
    #pragma unroll
    for (int nt = 0; nt < 8; nt++)
      Out[base + nt * 16 + lr] = o[nt][r] * invl + pa[nt][r] * invla;
  }
}

// ---------- 7. fp32 -> bf16 cast ----------
__global__ void k_cast(const float* __restrict__ in, unsigned short* __restrict__ outp, size_t n) {
  size_t i = (size_t)blockIdx.x * 256 + threadIdx.x;
  if (i < n) outp[i] = f2bf(in[i]);
}

// ---------- launcher ----------
extern "C" void kernel_launch(void* const* d_in, const int* in_sizes, int n_in,
                              void* d_out, int out_size, void* d_ws, size_t ws_size,
                              hipStream_t stream) {
  const float* hidden = (const float*)d_in[0];
  const float* Wq = (const float*)d_in[3];
  const float* Wk = (const float*)d_in[4];
  const float* Wv = (const float*)d_in[5];
  const float* Wo = (const float*)d_in[6];
  const float* Aq = (const float*)d_in[7];
  const float* gate = (const float*)d_in[8];
  float* out = (float*)d_out;

  char* ws = (char*)d_ws;
  size_t off = 0;
  auto alloc = [&](size_t bytes) -> void* {
    void* p = ws + off;
    off = (off + bytes + 255) & ~(size_t)255;
    return p;
  };
  unsigned short* wt   = (unsigned short*)alloc((size_t)4 * DMODEL * DMODEL * 2);
  unsigned short* xaug = (unsigned short*)alloc((size_t)MAUG * DMODEL * 2);
  float* qf = (float*)alloc((size_t)3 * MAUG * DMODEL * 4);  // qf|kf|vf contiguous
  float* kf = qf + (size_t)MAUG * DMODEL;
  float* vf = kf + (size_t)MAUG * DMODEL;
  unsigned short* qb  = (unsigned short*)alloc((size_t)NB * SEQ * DMODEL * 2);
  unsigned short* kb  = (unsigned short*)alloc((size_t)NB * SEQ * DMODEL * 2);
  unsigned short* vt  = (unsigned short*)alloc((size_t)NB * SEQ * DMODEL * 2);
  unsigned short* akb = (unsigned short*)alloc((size_t)NP * DMODEL * 2);
  unsigned short* avb = (unsigned short*)alloc((size_t)NP * DMODEL * 2);
  float* cost = (float*)alloc((size_t)SEQ * HD * 4);
  float* sint = (float*)alloc((size_t)SEQ * HD * 4);
  float* attn = qf;                           // reuse (qf dead after k_rope)
  unsigned short* ab = (unsigned short*)kf;   // reuse (kf dead after k_rope)

  k_tables<<<SEQ * 64 / 256, 256, 0, stream>>>(cost, sint);
  k_wt<<<dim3(64, 64, 4), 256, 0, stream>>>(Wq, Wk, Wv, Wo, wt);
  {
    size_t n = (size_t)MAUG * DMODEL;
    k_xaug<<<(unsigned)((n + 255) / 256), 256, 0, stream>>>(hidden, Aq, xaug);
  }
  k_gemm<<<dim3(16, 33, 3), 256, 0, stream>>>(xaug, wt, qf, MAUG, (size_t)MAUG * DMODEL);
  k_rope<<<MAUG, 256, 0, stream>>>(qf, kf, vf, cost, sint, qb, kb, vt, akb, avb);
  k_flash<<<dim3(SEQ / 64, NH, NB), 256, 0, stream>>>(qb, kb, vt, akb, avb, gate, attn);
  k_cast<<<(unsigned)(((size_t)NB * SEQ * DMODEL + 255) / 256), 256, 0, stream>>>(attn, ab, (size_t)NB * SEQ * DMODEL);
  k_gemm<<<dim3(16, 32, 1), 256, 0, stream>>>(ab, wt + (size_t)3 * DMODEL * DMODEL, out, NB * SEQ, 0);
}

// Round 2
// 715.063 us; speedup vs baseline: 1.3024x; 1.3024x over previous
//
#include <hip/hip_runtime.h>
#include <cstdint>
#include <cstddef>

typedef __bf16 bf16x8 __attribute__((ext_vector_type(8)));
typedef float  f32x4  __attribute__((ext_vector_type(4)));

__device__ __forceinline__ unsigned short f2bf(float f) {
  unsigned int u = __float_as_uint(f);
  u += 0x7FFF + ((u >> 16) & 1);
  return (unsigned short)(u >> 16);
}
__device__ __forceinline__ float bf2f(unsigned short u) {
  return __uint_as_float(((unsigned int)u) << 16);
}

#define SEQ 2048
#define DMODEL 2048
#define NH 16
#define HD 128
#define NB 2
#define NP 10
#define MAUG 4106
#define SCALE 0.08838834764831845f

#define GLOAD_LDS16(g, l) \
  __builtin_amdgcn_global_load_lds((__attribute__((address_space(1))) const void*)(g), \
                                   (__attribute__((address_space(3))) void*)(l), 16, 0, 0)

// ---------- 1. RoPE tables ----------
__global__ void k_tables(float* __restrict__ cost, float* __restrict__ sint) {
  int idx = blockIdx.x * 256 + threadIdx.x;
  if (idx >= SEQ * 64) return;
  int s = idx >> 6, i = idx & 63;
  double invf = exp(-((double)(2 * i) / 128.0) * log(10000.0));
  double a = (double)s * invf;
  float c = (float)cos(a), sn = (float)sin(a);
  cost[s * HD + i] = c;  cost[s * HD + 64 + i] = c;
  sint[s * HD + i] = sn; sint[s * HD + 64 + i] = sn;
}

// ---------- 2. weight transpose + cast ----------
__global__ __launch_bounds__(256) void k_wt(const float* __restrict__ W0,
                                            const float* __restrict__ W1,
                                            const float* __restrict__ W2,
                                            const float* __restrict__ W3,
                                            unsigned short* __restrict__ out) {
  __shared__ float tile[32][33];
  const float* W = (blockIdx.z == 0) ? W0 : (blockIdx.z == 1) ? W1 : (blockIdx.z == 2) ? W2 : W3;
  unsigned short* o = out + (size_t)blockIdx.z * DMODEL * DMODEL;
  int bx = blockIdx.x * 32, by = blockIdx.y * 32;
  int tx = threadIdx.x & 31, ty = threadIdx.x >> 5;
  #pragma unroll
  for (int j = 0; j < 32; j += 8)
    tile[ty + j][tx] = W[(size_t)(bx + ty + j) * DMODEL + by + tx];
  __syncthreads();
  #pragma unroll
  for (int j = 0; j < 32; j += 8)
    o[(size_t)(by + ty + j) * DMODEL + bx + tx] = f2bf(tile[tx][ty + j]);
}

// ---------- 3. X augmented + cast ----------
__global__ void k_xaug(const float* __restrict__ X, const float* __restrict__ Aq,
                       unsigned short* __restrict__ xaug) {
  size_t idx = (size_t)blockIdx.x * 256 + threadIdx.x;
  if (idx >= (size_t)MAUG * DMODEL) return;
  size_t row = idx >> 11;
  int col = (int)(idx & 2047);
  float v = (row < (size_t)NB * SEQ) ? X[idx] : Aq[(row - NB * SEQ) * DMODEL + col];
  xaug[idx] = f2bf(v);
}

// ---------- 4. MFMA GEMM (m97 structure: global_load_lds width-16) ----------
template<int BF16OUT>
__global__ __launch_bounds__(256) void k_gemm(const unsigned short* __restrict__ A,
                                              const unsigned short* __restrict__ Bt,
                                              void* __restrict__ Cv,
                                              int M, size_t c_stride_mat) {
  __shared__ unsigned short As[128 * 32];
  __shared__ unsigned short Bs[128 * 32];
  const int t = threadIdx.x;
  const int lane = t & 63, w = t >> 6;
  const int lr = lane & 15, quad = lane >> 4;
  const int wm = (w & 1) * 64, wn = (w >> 1) * 64;
  const int m0 = blockIdx.y * 128, n0 = blockIdx.x * 128;
  const unsigned short* Btz = Bt + (size_t)blockIdx.z * DMODEL * DMODEL;

  const int arow = t >> 2, ch = t & 3;
  const unsigned short* gA = A + (size_t)(m0 + arow) * DMODEL + ch * 8;
  const unsigned short* gB = Btz + (size_t)(n0 + arow) * DMODEL + ch * 8;
  unsigned short* lA0 = &As[arow * 32 + ch * 8];
  unsigned short* lA1 = &As[(64 + arow) * 32 + ch * 8];
  unsigned short* lB0 = &Bs[arow * 32 + ch * 8];
  unsigned short* lB1 = &Bs[(64 + arow) * 32 + ch * 8];

  f32x4 acc[4][4];
  #pragma unroll
  for (int i = 0; i < 4; i++)
    #pragma unroll
    for (int j = 0; j < 4; j++) acc[i][j] = (f32x4){0.f, 0.f, 0.f, 0.f};

  for (int kt = 0; kt < DMODEL / 32; kt++) {
    GLOAD_LDS16(gA, lA0);
    GLOAD_LDS16(gA + (size_t)64 * DMODEL, lA1);
    GLOAD_LDS16(gB, lB0);
    GLOAD_LDS16(gB + (size_t)64 * DMODEL, lB1);
    gA += 32; gB += 32;
    __syncthreads();
    bf16x8 af[4], bfv[4];
    #pragma unroll
    for (int mt = 0; mt < 4; mt++) af[mt] = *(const bf16x8*)&As[(wm + mt * 16 + lr) * 32 + quad * 8];
    #pragma unroll
    for (int nt = 0; nt < 4; nt++) bfv[nt] = *(const bf16x8*)&Bs[(wn + nt * 16 + lr) * 32 + quad * 8];
    #pragma unroll
    for (int mt = 0; mt < 4; mt++)
      #pragma unroll
      for (int nt = 0; nt < 4; nt++)
        acc[mt][nt] = __builtin_amdgcn_mfma_f32_16x16x32_bf16(af[mt], bfv[nt], acc[mt][nt], 0, 0, 0);
    __syncthreads();
  }
  #pragma unroll
  for (int mt = 0; mt < 4; mt++) {
    #pragma unroll
    for (int r = 0; r < 4; r++) {
      int row = m0 + wm + mt * 16 + quad * 4 + r;
      if (row < M) {
        if (BF16OUT) {
          unsigned short* C = (unsigned short*)Cv + (size_t)blockIdx.z * c_stride_mat;
          #pragma unroll
          for (int nt = 0; nt < 4; nt++)
            C[(size_t)row * DMODEL + n0 + wn + nt * 16 + lr] = f2bf(acc[mt][nt][r]);
        } else {
          float* C = (float*)Cv + (size_t)blockIdx.z * c_stride_mat;
          #pragma unroll
          for (int nt = 0; nt < 4; nt++)
            C[(size_t)row * DMODEL + n0 + wn + nt * 16 + lr] = acc[mt][nt][r];
        }
      }
    }
  }
}

// ---------- 5. RoPE (bf16 in/out); adapter rows split off ----------
__global__ __launch_bounds__(256) void k_rope(const unsigned short* __restrict__ Qf,
                                              const unsigned short* __restrict__ Kf,
                                              const unsigned short* __restrict__ Vf,
                                              const float* __restrict__ cost, const float* __restrict__ sint,
                                              unsigned short* __restrict__ Qb, unsigned short* __restrict__ Kb,
                                              unsigned short* __restrict__ AKb, unsigned short* __restrict__ AVb) {
  int row = blockIdx.x;
  int t = threadIdx.x;
  int c0 = t * 8;
  size_t off = (size_t)row * DMODEL + c0;
  if (row < NB * SEQ) {
    int s = row & (SEQ - 1);
    int d0 = c0 & (HD - 1);
    int po = (d0 < 64) ? 64 : -64;
    float sign = (d0 < 64) ? -1.f : 1.f;
    uint4 qv = *(const uint4*)&Qf[off];
    uint4 qp = *(const uint4*)&Qf[off + po];
    uint4 kv = *(const uint4*)&Kf[off];
    uint4 kp = *(const uint4*)&Kf[off + po];
    const unsigned short* qa = (const unsigned short*)&qv;
    const unsigned short* qb2 = (const unsigned short*)&qp;
    const unsigned short* ka = (const unsigned short*)&kv;
    const unsigned short* kb2 = (const unsigned short*)&kp;
    unsigned short oq[8], ok[8];
    #pragma unroll
    for (int j = 0; j < 8; j++) {
      float cv = cost[s * HD + d0 + j], sv = sint[s * HD + d0 + j];
      oq[j] = f2bf(bf2f(qa[j]) * cv + sign * bf2f(qb2[j]) * sv);
      ok[j] = f2bf(bf2f(ka[j]) * cv + sign * bf2f(kb2[j]) * sv);
    }
    *(uint4*)&Qb[off] = *(const uint4*)oq;
    *(uint4*)&Kb[off] = *(const uint4*)ok;
  } else {
    int p = row - NB * SEQ;
    *(uint4*)&AKb[(size_t)p * DMODEL + c0] = *(const uint4*)&Kf[off];
    *(uint4*)&AVb[(size_t)p * DMODEL + c0] = *(const uint4*)&Vf[off];
  }
}

// ---------- 6. V transpose via LDS: Vf[b*S+s][h*HD+d] -> Vt[(b,h,d)][s] ----------
__global__ __launch_bounds__(256) void k_vt(const unsigned short* __restrict__ Vf,
                                            unsigned short* __restrict__ Vt) {
  __shared__ unsigned short tile[64][72];
  const int t = threadIdx.x;
  int s0 = blockIdx.x * 64;
  int d0 = blockIdx.y * 64;
  int b = blockIdx.z >> 4, h = blockIdx.z & 15;
  #pragma unroll
  for (int j = t; j < 512; j += 256) {
    int row = j >> 3, ch = j & 7;
    *(uint4*)&tile[row][ch * 8] =
      *(const uint4*)&Vf[(size_t)(b * SEQ + s0 + row) * DMODEL + h * HD + d0 + ch * 8];
  }
  __syncthreads();
  #pragma unroll
  for (int j = t; j < 512; j += 256) {
    int dr = j >> 3, ch = j & 7;
    unsigned short tmp[8];
    #pragma unroll
    for (int k = 0; k < 8; k++) tmp[k] = tile[ch * 8 + k][dr];
    *(uint4*)&Vt[((size_t)((b * NH + h) * HD + d0 + dr)) * SEQ + s0 + ch * 8] = *(const uint4*)tmp;
  }
}

// ---------- 7. flash attention + fused adapter, Q-tile 128 ----------
#define KSTR 136
#define VSTR 72
#define PSTR 72

__global__ __launch_bounds__(256) void k_flash(const unsigned short* __restrict__ Qb,
                                               const unsigned short* __restrict__ Kb,
                                               const unsigned short* __restrict__ Vt,
                                               const unsigned short* __restrict__ AKb,
                                               const unsigned short* __restrict__ AVb,
                                               const float* __restrict__ gate,
                                               unsigned short* __restrict__ Out) {
  const int qt = (gridDim.x - 1) - blockIdx.x;   // heavy tiles first
  const int h  = blockIdx.y;
  const int b  = blockIdx.z;
  const int t = threadIdx.x, w = t >> 6, lane = t & 63;
  const int lr = lane & 15, quad = lane >> 4;

  __shared__ unsigned short Ks[64 * KSTR];
  __shared__ unsigned short Vs[128 * VSTR];
  __shared__ unsigned short Ps[4][32 * PSTR];

  const int row_base = qt * 128 + w * 32;   // wave's 32 q-rows

  bf16x8 qf[2][4];
  #pragma unroll
  for (int mt = 0; mt < 2; mt++)
    #pragma unroll
    for (int kk = 0; kk < 4; kk++)
      qf[mt][kk] = *(const bf16x8*)&Qb[((size_t)(b * SEQ + row_base + mt * 16 + lr)) * DMODEL
                                       + h * HD + kk * 32 + quad * 8];

  f32x4 o[2][8];
  #pragma unroll
  for (int mt = 0; mt < 2; mt++)
    #pragma unroll
    for (int nt = 0; nt < 8; nt++) o[mt][nt] = (f32x4){0.f, 0.f, 0.f, 0.f};
  float m_i[2][4], l_i[2][4];
  #pragma unroll
  for (int mt = 0; mt < 2; mt++)
    #pragma unroll
    for (int r = 0; r < 4; r++) { m_i[mt][r] = -__builtin_inff(); l_i[mt][r] = 0.f; }

  const int ktmax = 2 * qt + 2;
  for (int kt = 0; kt < ktmax; kt++) {
    __syncthreads();
    #pragma unroll
    for (int i = t; i < 1024; i += 256) {
      int row = i >> 4, ch2 = i & 15;
      *(uint4*)&Ks[row * KSTR + ch2 * 8] =
        *(const uint4*)&Kb[((size_t)(b * SEQ + kt * 64 + row)) * DMODEL + h * HD + ch2 * 8];
    }
    #pragma unroll
    for (int i = t; i < 1024; i += 256) {
      int d = i >> 3, ch2 = i & 7;
      *(uint4*)&Vs[d * VSTR + ch2 * 8] =
        *(const uint4*)&Vt[((size_t)((b * NH + h) * HD + d)) * SEQ + kt * 64 + ch2 * 8];
    }
    __syncthreads();

    // S = Q K^T for both m-tiles (B-frag shared)
    f32x4 s4[2][4];
    #pragma unroll
    for (int mt = 0; mt < 2; mt++)
      #pragma unroll
      for (int nt = 0; nt < 4; nt++) s4[mt][nt] = (f32x4){0.f, 0.f, 0.f, 0.f};
    #pragma unroll
    for (int nt = 0; nt < 4; nt++)
      #pragma unroll
      for (int kk = 0; kk < 4; kk++) {
        bf16x8 bv = *(const bf16x8*)&Ks[(nt * 16 + lr) * KSTR + kk * 32 + quad * 8];
        s4[0][nt] = __builtin_amdgcn_mfma_f32_16x16x32_bf16(qf[0][kk], bv, s4[0][nt], 0, 0, 0);
        s4[1][nt] = __builtin_amdgcn_mfma_f32_16x16x32_bf16(qf[1][kk], bv, s4[1][nt], 0, 0, 0);
      }

    const int maybe_mask = (kt * 64 + 63 > row_base);
    #pragma unroll
    for (int mt = 0; mt < 2; mt++) {
      #pragma unroll
      for (int nt = 0; nt < 4; nt++) s4[mt][nt] = s4[mt][nt] * SCALE;
      if (maybe_mask) {
        #pragma unroll
        for (int nt = 0; nt < 4; nt++) {
          int col = kt * 64 + nt * 16 + lr;
          #pragma unroll
          for (int r = 0; r < 4; r++)
            if (col > row_base + mt * 16 + quad * 4 + r) s4[mt][nt][r] = -__builtin_inff();
        }
      }
      #pragma unroll
      for (int r = 0; r < 4; r++) {
        float tm = fmaxf(fmaxf(s4[mt][0][r], s4[mt][1][r]), fmaxf(s4[mt][2][r], s4[mt][3][r]));
        #pragma unroll
        for (int off = 1; off < 16; off <<= 1) tm = fmaxf(tm, __shfl_xor(tm, off, 64));
        float mnew = fmaxf(m_i[mt][r], tm);
        float p0 = __expf(s4[mt][0][r] - mnew), p1 = __expf(s4[mt][1][r] - mnew);
        float p2 = __expf(s4[mt][2][r] - mnew), p3 = __expf(s4[mt][3][r] - mnew);
        s4[mt][0][r] = p0; s4[mt][1][r] = p1; s4[mt][2][r] = p2; s4[mt][3][r] = p3;
        float sum = p0 + p1 + p2 + p3;
        #pragma unroll
        for (int off = 1; off < 16; off <<= 1) sum += __shfl_xor(sum, off, 64);
        float alpha = __expf(m_i[mt][r] - mnew);
        l_i[mt][r] = alpha * l_i[mt][r] + sum;
        m_i[mt][r] = mnew;
        #pragma unroll
        for (int nt = 0; nt < 8; nt++) o[mt][nt][r] *= alpha;
      }
      #pragma unroll
      for (int nt = 0; nt < 4; nt++)
        #pragma unroll
        for (int r = 0; r < 4; r++)
          Ps[w][(mt * 16 + quad * 4 + r) * PSTR + nt * 16 + lr] = f2bf(s4[mt][nt][r]);
    }
    // O += P V (Ps is wave-private: no barrier needed)
    #pragma unroll
    for (int kk2 = 0; kk2 < 2; kk2++) {
      bf16x8 af0 = *(const bf16x8*)&Ps[w][(lr) * PSTR + kk2 * 32 + quad * 8];
      bf16x8 af1 = *(const bf16x8*)&Ps[w][(16 + lr) * PSTR + kk2 * 32 + quad * 8];
      #pragma unroll
      for (int nt = 0; nt < 8; nt++) {
        bf16x8 bv = *(const bf16x8*)&Vs[(nt * 16 + lr) * VSTR + kk2 * 32 + quad * 8];
        o[0][nt] = __builtin_amdgcn_mfma_f32_16x16x32_bf16(af0, bv, o[0][nt], 0, 0, 0);
        o[1][nt] = __builtin_amdgcn_mfma_f32_16x16x32_bf16(af1, bv, o[1][nt], 0, 0, 0);
      }
    }
  }

  // ---- adapter (reuse Ks/Vs) ----
  __syncthreads();
  for (int i = t; i < 16 * 128; i += 256) {
    int p = i >> 7, d = i & 127;
    Ks[p * KSTR + d] = (p < NP) ? AKb[(size_t)p * DMODEL + h * HD + d] : (unsigned short)0;
  }
  for (int i = t; i < 128 * 32; i += 256) {
    int d = i >> 5, p = i & 31;
    Vs[d * VSTR + p] = (p < NP) ? AVb[(size_t)p * DMODEL + h * HD + d] : (unsigned short)0;
  }
  __syncthreads();

  const float g = gate[h];
  #pragma unroll
  for (int mt = 0; mt < 2; mt++) {
    f32x4 as4 = (f32x4){0.f, 0.f, 0.f, 0.f};
    #pragma unroll
    for (int kk = 0; kk < 4; kk++) {
      bf16x8 bv = *(const bf16x8*)&Ks[lr * KSTR + kk * 32 + quad * 8];
      as4 = __builtin_amdgcn_mfma_f32_16x16x32_bf16(qf[mt][kk], bv, as4, 0, 0, 0);
    }
    as4 = as4 * SCALE;
    if (lr >= NP) {
      #pragma unroll
      for (int r = 0; r < 4; r++) as4[r] = -__builtin_inff();
    }
    float al[4];
    #pragma unroll
    for (int r = 0; r < 4; r++) {
      float tm = as4[r];
      #pragma unroll
      for (int off = 1; off < 16; off <<= 1) tm = fmaxf(tm, __shfl_xor(tm, off, 64));
      float p = __expf(as4[r] - tm);
      as4[r] = p;
      float sum = p;
      #pragma unroll
      for (int off = 1; off < 16; off <<= 1) sum += __shfl_xor(sum, off, 64);
      al[r] = sum;
    }
    #pragma unroll
    for (int r = 0; r < 4; r++) {
      Ps[w][(mt * 16 + quad * 4 + r) * PSTR + lr] = f2bf(as4[r]);
      Ps[w][(mt * 16 + quad * 4 + r) * PSTR + 16 + lr] = 0;
    }
    float invl[4], invla[4];
    #pragma unroll
    for (int r = 0; r < 4; r++) { invl[r] = 1.0f / l_i[mt][r]; invla[r] = g / al[r]; }
    bf16x8 af = *(const bf16x8*)&Ps[w][(mt * 16 + lr) * PSTR + quad * 8];
    #pragma unroll
    for (int nt = 0; nt < 8; nt++) {
      bf16x8 bv = *(const bf16x8*)&Vs[(nt * 16 + lr) * VSTR + quad * 8];
      f32x4 pa = __builtin_amdgcn_mfma_f32_16x16x32_bf16(af, bv, (f32x4){0.f, 0.f, 0.f, 0.f}, 0, 0, 0);
      #pragma unroll
      for (int r = 0; r < 4; r++) o[mt][nt][r] = o[mt][nt][r] * invl[r] + pa[r] * invla[r];
    }
    #pragma unroll
    for (int r = 0; r < 4; r++) {
      int srow = row_base + mt * 16 + quad * 4 + r;
      size_t base = ((size_t)(b * SEQ + srow)) * DMODEL + h * HD;
      #pragma unroll
      for (int nt = 0; nt < 8; nt++)
        Out[base + nt * 16 + lr] = f2bf(o[mt][nt][r]);
    }
  }
}

// ---------- launcher ----------
extern "C" void kernel_launch(void* const* d_in, const int* in_sizes, int n_in,
                              void* d_out, int out_size, void* d_ws, size_t ws_size,
                              hipStream_t stream) {
  const float* hidden = (const float*)d_in[0];
  const float* Wq = (const float*)d_in[3];
  const float* Wk = (const float*)d_in[4];
  const float* Wv = (const float*)d_in[5];
  const float* Wo = (const float*)d_in[6];
  const float* Aq = (const float*)d_in[7];
  const float* gate = (const float*)d_in[8];
  float* out = (float*)d_out;

  char* ws = (char*)d_ws;
  size_t off = 0;
  auto alloc = [&](size_t bytes) -> void* {
    void* p = ws + off;
    off = (off + bytes + 255) & ~(size_t)255;
    return p;
  };
  unsigned short* wt   = (unsigned short*)alloc((size_t)4 * DMODEL * DMODEL * 2);
  unsigned short* xaug = (unsigned short*)alloc((size_t)MAUG * DMODEL * 2);
  unsigned short* qkvb = (unsigned short*)alloc((size_t)3 * MAUG * DMODEL * 2);
  unsigned short* qf = qkvb;
  unsigned short* kf = qkvb + (size_t)MAUG * DMODEL;
  unsigned short* vf = kf + (size_t)MAUG * DMODEL;
  unsigned short* qb  = (unsigned short*)alloc((size_t)NB * SEQ * DMODEL * 2);
  unsigned short* kb  = (unsigned short*)alloc((size_t)NB * SEQ * DMODEL * 2);
  unsigned short* vt  = (unsigned short*)alloc((size_t)NB * SEQ * DMODEL * 2);
  unsigned short* akb = (unsigned short*)alloc((size_t)NP * DMODEL * 2);
  unsigned short* avb = (unsigned short*)alloc((size_t)NP * DMODEL * 2);
  float* cost = (float*)alloc((size_t)SEQ * HD * 4);
  float* sint = (float*)alloc((size_t)SEQ * HD * 4);
  unsigned short* ab = qf;   // reuse: qf dead after k_rope

  k_tables<<<SEQ * 64 / 256, 256, 0, stream>>>(cost, sint);
  k_wt<<<dim3(64, 64, 4), 256, 0, stream>>>(Wq, Wk, Wv, Wo, wt);
  {
    size_t n = (size_t)MAUG * DMODEL;
    k_xaug<<<(unsigned)((n + 255) / 256), 256, 0, stream>>>(hidden, Aq, xaug);
  }
  k_gemm<1><<<dim3(16, 33, 3), 256, 0, stream>>>(xaug, wt, qkvb, MAUG, (size_t)MAUG * DMODEL);
  k_rope<<<MAUG, 256, 0, stream>>>(qf, kf, vf, cost, sint, qb, kb, akb, avb);
  k_vt<<<dim3(32, 2, 32), 256, 0, stream>>>(vf, vt);
  k_flash<<<dim3(16, 16, 2), 256, 0, stream>>>(qb, kb, vt, akb, avb, gate, ab);
  k_gemm<0><<<dim3(16, 32, 1), 256, 0, stream>>>(ab, wt + (size_t)3 * DMODEL * DMODEL, out, NB * SEQ, 0);
}

// Round 3
// 639.158 us; speedup vs baseline: 1.4571x; 1.1188x over previous
//
#include <hip/hip_runtime.h>
#include <cstdint>
#include <cstddef>

typedef __bf16 bf16x8 __attribute__((ext_vector_type(8)));
typedef float  f32x4  __attribute__((ext_vector_type(4)));

__device__ __forceinline__ unsigned short f2bf(float f) {
  unsigned int u = __float_as_uint(f);
  u += 0x7FFF + ((u >> 16) & 1);
  return (unsigned short)(u >> 16);
}
__device__ __forceinline__ float bf2f(unsigned short u) {
  return __uint_as_float(((unsigned int)u) << 16);
}

#define SEQ 2048
#define DMODEL 2048
#define NH 16
#define HD 128
#define NB 2
#define NP 10
#define MAUG 4106
#define SCALE 0.08838834764831845f
#define SCALEL2 (0.08838834764831845f * 1.44269504088896340f)

#define GLOAD_LDS16(g, l) \
  __builtin_amdgcn_global_load_lds((__attribute__((address_space(1))) const void*)(g), \
                                   (__attribute__((address_space(3))) void*)(l), 16, 0, 0)

// ---------- 1. RoPE tables ----------
__global__ void k_tables(float* __restrict__ cost, float* __restrict__ sint) {
  int idx = blockIdx.x * 256 + threadIdx.x;
  if (idx >= SEQ * 64) return;
  int s = idx >> 6, i = idx & 63;
  double invf = exp(-((double)(2 * i) / 128.0) * log(10000.0));
  double a = (double)s * invf;
  float c = (float)cos(a), sn = (float)sin(a);
  cost[s * HD + i] = c;  cost[s * HD + 64 + i] = c;
  sint[s * HD + i] = sn; sint[s * HD + 64 + i] = sn;
}

// ---------- 2. weight transpose + cast ----------
__global__ __launch_bounds__(256) void k_wt(const float* __restrict__ W0,
                                            const float* __restrict__ W1,
                                            const float* __restrict__ W2,
                                            const float* __restrict__ W3,
                                            unsigned short* __restrict__ out) {
  __shared__ float tile[32][33];
  const float* W = (blockIdx.z == 0) ? W0 : (blockIdx.z == 1) ? W1 : (blockIdx.z == 2) ? W2 : W3;
  unsigned short* o = out + (size_t)blockIdx.z * DMODEL * DMODEL;
  int bx = blockIdx.x * 32, by = blockIdx.y * 32;
  int tx = threadIdx.x & 31, ty = threadIdx.x >> 5;
  #pragma unroll
  for (int j = 0; j < 32; j += 8)
    tile[ty + j][tx] = W[(size_t)(bx + ty + j) * DMODEL + by + tx];
  __syncthreads();
  #pragma unroll
  for (int j = 0; j < 32; j += 8)
    o[(size_t)(by + ty + j) * DMODEL + bx + tx] = f2bf(tile[tx][ty + j]);
}

// ---------- 3. X augmented + cast ----------
__global__ void k_xaug(const float* __restrict__ X, const float* __restrict__ Aq,
                       unsigned short* __restrict__ xaug) {
  size_t idx = (size_t)blockIdx.x * 256 + threadIdx.x;
  if (idx >= (size_t)MAUG * DMODEL) return;
  size_t row = idx >> 11;
  int col = (int)(idx & 2047);
  float v = (row < (size_t)NB * SEQ) ? X[idx] : Aq[(row - NB * SEQ) * DMODEL + col];
  xaug[idx] = f2bf(v);
}

// ---------- 4. MFMA GEMM, global_load_lds + XOR-swizzled LDS ----------
// LDS slot layout: slot = row*4 + (c ^ ((row>>1)&3)), 16B chunks, no padding.
template<int BF16OUT>
__global__ __launch_bounds__(256) void k_gemm(const unsigned short* __restrict__ A,
                                              const unsigned short* __restrict__ Bt,
                                              void* __restrict__ Cv,
                                              int M, size_t c_stride_mat) {
  __shared__ unsigned short As[128 * 32];
  __shared__ unsigned short Bs[128 * 32];
  const int t = threadIdx.x;
  const int lane = t & 63, w = t >> 6;
  const int lr = lane & 15, quad = lane >> 4;
  const int wm = (w & 1) * 64, wn = (w >> 1) * 64;
  const int m0 = blockIdx.y * 128, n0 = blockIdx.x * 128;
  const unsigned short* Btz = Bt + (size_t)blockIdx.z * DMODEL * DMODEL;

  const int arow = t >> 2;
  const int csw = (t & 3) ^ ((t >> 3) & 3);   // swizzled source chunk
  const unsigned short* gA = A + (size_t)(m0 + arow) * DMODEL + csw * 8;
  const unsigned short* gB = Btz + (size_t)(n0 + arow) * DMODEL + csw * 8;
  unsigned short* lA0 = &As[t * 8];
  unsigned short* lA1 = &As[2048 + t * 8];
  unsigned short* lB0 = &Bs[t * 8];
  unsigned short* lB1 = &Bs[2048 + t * 8];

  const int sw = (lr >> 1) & 3;   // fragment-read chunk swizzle

  f32x4 acc[4][4];
  #pragma unroll
  for (int i = 0; i < 4; i++)
    #pragma unroll
    for (int j = 0; j < 4; j++) acc[i][j] = (f32x4){0.f, 0.f, 0.f, 0.f};

  for (int kt = 0; kt < DMODEL / 32; kt++) {
    GLOAD_LDS16(gA, lA0);
    GLOAD_LDS16(gA + (size_t)64 * DMODEL, lA1);
    GLOAD_LDS16(gB, lB0);
    GLOAD_LDS16(gB + (size_t)64 * DMODEL, lB1);
    gA += 32; gB += 32;
    __syncthreads();
    bf16x8 af[4], bfv[4];
    #pragma unroll
    for (int mt = 0; mt < 4; mt++)
      af[mt] = *(const bf16x8*)&As[(wm + mt * 16 + lr) * 32 + (quad ^ sw) * 8];
    #pragma unroll
    for (int nt = 0; nt < 4; nt++)
      bfv[nt] = *(const bf16x8*)&Bs[(wn + nt * 16 + lr) * 32 + (quad ^ sw) * 8];
    #pragma unroll
    for (int mt = 0; mt < 4; mt++)
      #pragma unroll
      for (int nt = 0; nt < 4; nt++)
        acc[mt][nt] = __builtin_amdgcn_mfma_f32_16x16x32_bf16(af[mt], bfv[nt], acc[mt][nt], 0, 0, 0);
    __syncthreads();
  }
  #pragma unroll
  for (int mt = 0; mt < 4; mt++) {
    #pragma unroll
    for (int r = 0; r < 4; r++) {
      int row = m0 + wm + mt * 16 + quad * 4 + r;
      if (row < M) {
        if (BF16OUT) {
          unsigned short* C = (unsigned short*)Cv + (size_t)blockIdx.z * c_stride_mat;
          #pragma unroll
          for (int nt = 0; nt < 4; nt++)
            C[(size_t)row * DMODEL + n0 + wn + nt * 16 + lr] = f2bf(acc[mt][nt][r]);
        } else {
          float* C = (float*)Cv + (size_t)blockIdx.z * c_stride_mat;
          #pragma unroll
          for (int nt = 0; nt < 4; nt++)
            C[(size_t)row * DMODEL + n0 + wn + nt * 16 + lr] = acc[mt][nt][r];
        }
      }
    }
  }
}

// ---------- 5. RoPE (bf16 in/out); adapter rows split off ----------
__global__ __launch_bounds__(256) void k_rope(const unsigned short* __restrict__ Qf,
                                              const unsigned short* __restrict__ Kf,
                                              const unsigned short* __restrict__ Vf,
                                              const float* __restrict__ cost, const float* __restrict__ sint,
                                              unsigned short* __restrict__ Qb, unsigned short* __restrict__ Kb,
                                              unsigned short* __restrict__ AKb, unsigned short* __restrict__ AVb) {
  int row = blockIdx.x;
  int t = threadIdx.x;
  int c0 = t * 8;
  size_t off = (size_t)row * DMODEL + c0;
  if (row < NB * SEQ) {
    int s = row & (SEQ - 1);
    int d0 = c0 & (HD - 1);
    int po = (d0 < 64) ? 64 : -64;
    float sign = (d0 < 64) ? -1.f : 1.f;
    uint4 qv = *(const uint4*)&Qf[off];
    uint4 qp = *(const uint4*)&Qf[off + po];
    uint4 kv = *(const uint4*)&Kf[off];
    uint4 kp = *(const uint4*)&Kf[off + po];
    const unsigned short* qa = (const unsigned short*)&qv;
    const unsigned short* qb2 = (const unsigned short*)&qp;
    const unsigned short* ka = (const unsigned short*)&kv;
    const unsigned short* kb2 = (const unsigned short*)&kp;
    unsigned short oq[8], ok[8];
    #pragma unroll
    for (int j = 0; j < 8; j++) {
      float cv = cost[s * HD + d0 + j], sv = sint[s * HD + d0 + j];
      oq[j] = f2bf(bf2f(qa[j]) * cv + sign * bf2f(qb2[j]) * sv);
      ok[j] = f2bf(bf2f(ka[j]) * cv + sign * bf2f(kb2[j]) * sv);
    }
    *(uint4*)&Qb[off] = *(const uint4*)oq;
    *(uint4*)&Kb[off] = *(const uint4*)ok;
  } else {
    int p = row - NB * SEQ;
    *(uint4*)&AKb[(size_t)p * DMODEL + c0] = *(const uint4*)&Kf[off];
    *(uint4*)&AVb[(size_t)p * DMODEL + c0] = *(const uint4*)&Vf[off];
  }
}

// ---------- 6. V transpose via LDS ----------
__global__ __launch_bounds__(256) void k_vt(const unsigned short* __restrict__ Vf,
                                            unsigned short* __restrict__ Vt) {
  __shared__ unsigned short tile[64][72];
  const int t = threadIdx.x;
  int s0 = blockIdx.x * 64;
  int d0 = blockIdx.y * 64;
  int b = blockIdx.z >> 4, h = blockIdx.z & 15;
  #pragma unroll
  for (int j = t; j < 512; j += 256) {
    int row = j >> 3, ch = j & 7;
    *(uint4*)&tile[row][ch * 8] =
      *(const uint4*)&Vf[(size_t)(b * SEQ + s0 + row) * DMODEL + h * HD + d0 + ch * 8];
  }
  __syncthreads();
  #pragma unroll
  for (int j = t; j < 512; j += 256) {
    int dr = j >> 3, ch = j & 7;
    unsigned short tmp[8];
    #pragma unroll
    for (int k = 0; k < 8; k++) tmp[k] = tile[ch * 8 + k][dr];
    *(uint4*)&Vt[((size_t)((b * NH + h) * HD + d0 + dr)) * SEQ + s0 + ch * 8] = *(const uint4*)tmp;
  }
}

// ---------- 7. flash attention + fused adapter ----------
// Ks: 64 rows x 16 chunks, slot = row*16 + (c ^ (row&15))
// Vs: 128 rows x 8 chunks,  slot = d*8  + (c ^ (d&7))
#define PSTR 68

__global__ __launch_bounds__(256, 3) void k_flash(const unsigned short* __restrict__ Qb,
                                               const unsigned short* __restrict__ Kb,
                                               const unsigned short* __restrict__ Vt,
                                               const unsigned short* __restrict__ AKb,
                                               const unsigned short* __restrict__ AVb,
                                               const float* __restrict__ gate,
                                               unsigned short* __restrict__ Out) {
  const int qt = blockIdx.z ? blockIdx.x : (15 - blockIdx.x);  // balance: paired blocks sum to const
  const int h  = blockIdx.y;
  const int b  = blockIdx.z;
  const int t = threadIdx.x, w = t >> 6, lane = t & 63;
  const int lr = lane & 15, quad = lane >> 4;

  __shared__ unsigned short Ks[64 * 128];
  __shared__ unsigned short Vs[128 * 64];
  __shared__ unsigned short Ps[4][32 * PSTR];

  const int row_base = qt * 128 + w * 32;

  bf16x8 qf[2][4];
  #pragma unroll
  for (int mt = 0; mt < 2; mt++)
    #pragma unroll
    for (int kk = 0; kk < 4; kk++)
      qf[mt][kk] = *(const bf16x8*)&Qb[((size_t)(b * SEQ + row_base + mt * 16 + lr)) * DMODEL
                                       + h * HD + kk * 32 + quad * 8];

  f32x4 o[2][8];
  #pragma unroll
  for (int mt = 0; mt < 2; mt++)
    #pragma unroll
    for (int nt = 0; nt < 8; nt++) o[mt][nt] = (f32x4){0.f, 0.f, 0.f, 0.f};
  float m_i[2][4], l_i[2][4];
  #pragma unroll
  for (int mt = 0; mt < 2; mt++)
    #pragma unroll
    for (int r = 0; r < 4; r++) { m_i[mt][r] = -__builtin_inff(); l_i[mt][r] = 0.f; }

  // staging addresses (constant per thread except kt offset)
  const int krow = t >> 4, kc = (t & 15) ^ (krow & 15);          // K: 256 of 1024 slots per j-iter
  const int vd = t >> 3, vc = (t & 7) ^ (vd & 7);

  const int ktmax = 2 * qt + 2;
  for (int kt = 0; kt < ktmax; kt++) {
    __syncthreads();
    #pragma unroll
    for (int j = 0; j < 4; j++) {
      int row = krow + j * 16;
      int c = (t & 15) ^ (row & 15);
      GLOAD_LDS16(&Kb[((size_t)(b * SEQ + kt * 64 + row)) * DMODEL + h * HD + c * 8],
                  &Ks[(t + j * 256) * 8]);
    }
    #pragma unroll
    for (int j = 0; j < 4; j++) {
      int d = vd + j * 32;
      GLOAD_LDS16(&Vt[((size_t)((b * NH + h) * HD + d)) * SEQ + kt * 64 + vc * 8],
                  &Vs[(t + j * 256) * 8]);
    }
    __syncthreads();

    // S = Q K^T
    f32x4 s4[2][4];
    #pragma unroll
    for (int mt = 0; mt < 2; mt++)
      #pragma unroll
      for (int nt = 0; nt < 4; nt++) s4[mt][nt] = (f32x4){0.f, 0.f, 0.f, 0.f};
    #pragma unroll
    for (int nt = 0; nt < 4; nt++)
      #pragma unroll
      for (int kk = 0; kk < 4; kk++) {
        bf16x8 bv = *(const bf16x8*)&Ks[((nt * 16 + lr) * 16 + ((kk * 4 + quad) ^ lr)) * 8];
        s4[0][nt] = __builtin_amdgcn_mfma_f32_16x16x32_bf16(qf[0][kk], bv, s4[0][nt], 0, 0, 0);
        s4[1][nt] = __builtin_amdgcn_mfma_f32_16x16x32_bf16(qf[1][kk], bv, s4[1][nt], 0, 0, 0);
      }

    const int maybe_mask = (kt * 64 + 63 > row_base);
    #pragma unroll
    for (int mt = 0; mt < 2; mt++) {
      #pragma unroll
      for (int nt = 0; nt < 4; nt++) s4[mt][nt] = s4[mt][nt] * SCALEL2;
      if (maybe_mask) {
        #pragma unroll
        for (int nt = 0; nt < 4; nt++) {
          int col = kt * 64 + nt * 16 + lr;
          #pragma unroll
          for (int r = 0; r < 4; r++)
            if (col > row_base + mt * 16 + quad * 4 + r) s4[mt][nt][r] = -__builtin_inff();
        }
      }
      #pragma unroll
      for (int r = 0; r < 4; r++) {
        float tm = fmaxf(fmaxf(s4[mt][0][r], s4[mt][1][r]), fmaxf(s4[mt][2][r], s4[mt][3][r]));
        #pragma unroll
        for (int off = 1; off < 16; off <<= 1) tm = fmaxf(tm, __shfl_xor(tm, off, 64));
        float mnew = fmaxf(m_i[mt][r], tm);
        float p0 = __builtin_amdgcn_exp2f(s4[mt][0][r] - mnew);
        float p1 = __builtin_amdgcn_exp2f(s4[mt][1][r] - mnew);
        float p2 = __builtin_amdgcn_exp2f(s4[mt][2][r] - mnew);
        float p3 = __builtin_amdgcn_exp2f(s4[mt][3][r] - mnew);
        s4[mt][0][r] = p0; s4[mt][1][r] = p1; s4[mt][2][r] = p2; s4[mt][3][r] = p3;
        float alpha = __builtin_amdgcn_exp2f(m_i[mt][r] - mnew);
        l_i[mt][r] = alpha * l_i[mt][r] + (p0 + p1) + (p2 + p3);  // lane-partial; reduced in epilogue
        m_i[mt][r] = mnew;
        #pragma unroll
        for (int nt = 0; nt < 8; nt++) o[mt][nt][r] *= alpha;
      }
      #pragma unroll
      for (int nt = 0; nt < 4; nt++)
        #pragma unroll
        for (int r = 0; r < 4; r++)
          Ps[w][(mt * 16 + quad * 4 + r) * PSTR + nt * 16 + lr] = f2bf(s4[mt][nt][r]);
    }
    // O += P V   (Ps wave-private; no barrier)
    #pragma unroll
    for (int kk2 = 0; kk2 < 2; kk2++) {
      bf16x8 af0 = *(const bf16x8*)&Ps[w][(lr) * PSTR + kk2 * 32 + quad * 8];
      bf16x8 af1 = *(const bf16x8*)&Ps[w][(16 + lr) * PSTR + kk2 * 32 + quad * 8];
      #pragma unroll
      for (int nt = 0; nt < 8; nt++) {
        bf16x8 bv = *(const bf16x8*)&Vs[((nt * 16 + lr) * 8 + ((kk2 * 4 + quad) ^ (lr & 7))) * 8];
        o[0][nt] = __builtin_amdgcn_mfma_f32_16x16x32_bf16(af0, bv, o[0][nt], 0, 0, 0);
        o[1][nt] = __builtin_amdgcn_mfma_f32_16x16x32_bf16(af1, bv, o[1][nt], 0, 0, 0);
      }
    }
  }

  // reduce the deferred row-sums
  #pragma unroll
  for (int mt = 0; mt < 2; mt++)
    #pragma unroll
    for (int r = 0; r < 4; r++) {
      float l = l_i[mt][r];
      #pragma unroll
      for (int off = 1; off < 16; off <<= 1) l += __shfl_xor(l, off, 64);
      l_i[mt][r] = l;
    }

  // ---- adapter (reuse Ks/Vs regions, plain strides — one-shot) ----
  __syncthreads();
  for (int i = t; i < 16 * 128; i += 256) {
    int p = i >> 7, d = i & 127;
    Ks[p * 128 + d] = (p < NP) ? AKb[(size_t)p * DMODEL + h * HD + d] : (unsigned short)0;
  }
  for (int i = t; i < 128 * 32; i += 256) {
    int d = i >> 5, p = i & 31;
    Vs[d * 32 + p] = (p < NP) ? AVb[(size_t)p * DMODEL + h * HD + d] : (unsigned short)0;
  }
  __syncthreads();

  const float g = gate[h];
  #pragma unroll
  for (int mt = 0; mt < 2; mt++) {
    f32x4 as4 = (f32x4){0.f, 0.f, 0.f, 0.f};
    #pragma unroll
    for (int kk = 0; kk < 4; kk++) {
      bf16x8 bv = *(const bf16x8*)&Ks[lr * 128 + kk * 32 + quad * 8];
      as4 = __builtin_amdgcn_mfma_f32_16x16x32_bf16(qf[mt][kk], bv, as4, 0, 0, 0);
    }
    as4 = as4 * SCALEL2;
    if (lr >= NP) {
      #pragma unroll
      for (int r = 0; r < 4; r++) as4[r] = -__builtin_inff();
    }
    float al[4];
    #pragma unroll
    for (int r = 0; r < 4; r++) {
      float tm = as4[r];
      #pragma unroll
      for (int off = 1; off < 16; off <<= 1) tm = fmaxf(tm, __shfl_xor(tm, off, 64));
      float p = __builtin_amdgcn_exp2f(as4[r] - tm);
      as4[r] = p;
      float sum = p;
      #pragma unroll
      for (int off = 1; off < 16; off <<= 1) sum += __shfl_xor(sum, off, 64);
      al[r] = sum;
    }
    #pragma unroll
    for (int r = 0; r < 4; r++) {
      Ps[w][(mt * 16 + quad * 4 + r) * PSTR + lr] = f2bf(as4[r]);
      Ps[w][(mt * 16 + quad * 4 + r) * PSTR + 16 + lr] = 0;
    }
    float invl[4], invla[4];
    #pragma unroll
    for (int r = 0; r < 4; r++) { invl[r] = 1.0f / l_i[mt][r]; invla[r] = g / al[r]; }
    bf16x8 af = *(const bf16x8*)&Ps[w][(mt * 16 + lr) * PSTR + quad * 8];
    #pragma unroll
    for (int nt = 0; nt < 8; nt++) {
      bf16x8 bv = *(const bf16x8*)&Vs[(nt * 16 + lr) * 32 + quad * 8];
      f32x4 pa = __builtin_amdgcn_mfma_f32_16x16x32_bf16(af, bv, (f32x4){0.f, 0.f, 0.f, 0.f}, 0, 0, 0);
      #pragma unroll
      for (int r = 0; r < 4; r++) o[mt][nt][r] = o[mt][nt][r] * invl[r] + pa[r] * invla[r];
    }
    #pragma unroll
    for (int r = 0; r < 4; r++) {
      int srow = row_base + mt * 16 + quad * 4 + r;
      size_t base = ((size_t)(b * SEQ + srow)) * DMODEL + h * HD;
      #pragma unroll
      for (int nt = 0; nt < 8; nt++)
        Out[base + nt * 16 + lr] = f2bf(o[mt][nt][r]);
    }
  }
}

// ---------- launcher ----------
extern "C" void kernel_launch(void* const* d_in, const int* in_sizes, int n_in,
                              void* d_out, int out_size, void* d_ws, size_t ws_size,
                              hipStream_t stream) {
  const float* hidden = (const float*)d_in[0];
  const float* Wq = (const float*)d_in[3];
  const float* Wk = (const float*)d_in[4];
  const float* Wv = (const float*)d_in[5];
  const float* Wo = (const float*)d_in[6];
  const float* Aq = (const float*)d_in[7];
  const float* gate = (const float*)d_in[8];
  float* out = (float*)d_out;

  char* ws = (char*)d_ws;
  size_t off = 0;
  auto alloc = [&](size_t bytes) -> void* {
    void* p = ws + off;
    off = (off + bytes + 255) & ~(size_t)255;
    return p;
  };
  unsigned short* wt   = (unsigned short*)alloc((size_t)4 * DMODEL * DMODEL * 2);
  unsigned short* xaug = (unsigned short*)alloc((size_t)MAUG * DMODEL * 2);
  unsigned short* qkvb = (unsigned short*)alloc((size_t)3 * MAUG * DMODEL * 2);
  unsigned short* qf = qkvb;
  unsigned short* kf = qkvb + (size_t)MAUG * DMODEL;
  unsigned short* vf = kf + (size_t)MAUG * DMODEL;
  unsigned short* qb  = (unsigned short*)alloc((size_t)NB * SEQ * DMODEL * 2);
  unsigned short* kb  = (unsigned short*)alloc((size_t)NB * SEQ * DMODEL * 2);
  unsigned short* vt  = (unsigned short*)alloc((size_t)NB * SEQ * DMODEL * 2);
  unsigned short* akb = (unsigned short*)alloc((size_t)NP * DMODEL * 2);
  unsigned short* avb = (unsigned short*)alloc((size_t)NP * DMODEL * 2);
  float* cost = (float*)alloc((size_t)SEQ * HD * 4);
  float* sint = (float*)alloc((size_t)SEQ * HD * 4);
  unsigned short* ab = qf;   // reuse: qf dead after k_rope

  k_tables<<<SEQ * 64 / 256, 256, 0, stream>>>(cost, sint);
  k_wt<<<dim3(64, 64, 4), 256, 0, stream>>>(Wq, Wk, Wv, Wo, wt);
  {
    size_t n = (size_t)MAUG * DMODEL;
    k_xaug<<<(unsigned)((n + 255) / 256), 256, 0, stream>>>(hidden, Aq, xaug);
  }
  k_gemm<1><<<dim3(16, 33, 3), 256, 0, stream>>>(xaug, wt, qkvb, MAUG, (size_t)MAUG * DMODEL);
  k_rope<<<MAUG, 256, 0, stream>>>(qf, kf, vf, cost, sint, qb, kb, akb, avb);
  k_vt<<<dim3(32, 2, 32), 256, 0, stream>>>(vf, vt);
  k_flash<<<dim3(16, 16, 2), 256, 0, stream>>>(qb, kb, vt, akb, avb, gate, ab);
  k_gemm<0><<<dim3(16, 32, 1), 256, 0, stream>>>(ab, wt + (size_t)3 * DMODEL * DMODEL, out, NB * SEQ, 0);
}

// Round 4
// 579.030 us; speedup vs baseline: 1.6084x; 1.1038x over previous
//
#include <hip/hip_runtime.h>
#include <cstdint>
#include <cstddef>

typedef __bf16 bf16x8 __attribute__((ext_vector_type(8)));
typedef float  f32x4  __attribute__((ext_vector_type(4)));

__device__ __forceinline__ unsigned short f2bf(float f) {
  unsigned int u = __float_as_uint(f);
  u += 0x7FFF + ((u >> 16) & 1);
  return (unsigned short)(u >> 16);
}
__device__ __forceinline__ float bf2f(unsigned short u) {
  return __uint_as_float(((unsigned int)u) << 16);
}

#define SEQ 2048
#define DMODEL 2048
#define NH 16
#define HD 128
#define NB 2
#define NP 10
#define MAUG 4106
#define SCALEL2 (0.08838834764831845f * 1.44269504088896340f)

#define GLOAD_LDS16(g, l) \
  __builtin_amdgcn_global_load_lds((__attribute__((address_space(1))) const void*)(g), \
                                   (__attribute__((address_space(3))) void*)(l), 16, 0, 0)

// ---------- 1. RoPE tables ----------
__global__ void k_tables(float* __restrict__ cost, float* __restrict__ sint) {
  int idx = blockIdx.x * 256 + threadIdx.x;
  if (idx >= SEQ * 64) return;
  int s = idx >> 6, i = idx & 63;
  double invf = exp(-((double)(2 * i) / 128.0) * log(10000.0));
  double a = (double)s * invf;
  float c = (float)cos(a), sn = (float)sin(a);
  cost[s * HD + i] = c;  cost[s * HD + 64 + i] = c;
  sint[s * HD + i] = sn; sint[s * HD + 64 + i] = sn;
}

// ---------- 2. weight transpose + cast ----------
__global__ __launch_bounds__(256) void k_wt(const float* __restrict__ W0,
                                            const float* __restrict__ W1,
                                            const float* __restrict__ W2,
                                            const float* __restrict__ W3,
                                            unsigned short* __restrict__ out) {
  __shared__ float tile[32][33];
  const float* W = (blockIdx.z == 0) ? W0 : (blockIdx.z == 1) ? W1 : (blockIdx.z == 2) ? W2 : W3;
  unsigned short* o = out + (size_t)blockIdx.z * DMODEL * DMODEL;
  int bx = blockIdx.x * 32, by = blockIdx.y * 32;
  int tx = threadIdx.x & 31, ty = threadIdx.x >> 5;
  #pragma unroll
  for (int j = 0; j < 32; j += 8)
    tile[ty + j][tx] = W[(size_t)(bx + ty + j) * DMODEL + by + tx];
  __syncthreads();
  #pragma unroll
  for (int j = 0; j < 32; j += 8)
    o[(size_t)(by + ty + j) * DMODEL + bx + tx] = f2bf(tile[tx][ty + j]);
}

// ---------- 3. X augmented + cast ----------
__global__ void k_xaug(const float* __restrict__ X, const float* __restrict__ Aq,
                       unsigned short* __restrict__ xaug) {
  size_t idx = (size_t)blockIdx.x * 256 + threadIdx.x;
  if (idx >= (size_t)MAUG * DMODEL) return;
  size_t row = idx >> 11;
  int col = (int)(idx & 2047);
  float v = (row < (size_t)NB * SEQ) ? X[idx] : Aq[(row - NB * SEQ) * DMODEL + col];
  xaug[idx] = f2bf(v);
}

// ---------- 4. MFMA GEMM, global_load_lds + XOR-swizzled LDS ----------
template<int BF16OUT>
__global__ __launch_bounds__(256) void k_gemm(const unsigned short* __restrict__ A,
                                              const unsigned short* __restrict__ Bt,
                                              void* __restrict__ Cv,
                                              int M, size_t c_stride_mat) {
  __shared__ unsigned short As[128 * 32];
  __shared__ unsigned short Bs[128 * 32];
  const int t = threadIdx.x;
  const int lane = t & 63, w = t >> 6;
  const int lr = lane & 15, quad = lane >> 4;
  const int wm = (w & 1) * 64, wn = (w >> 1) * 64;
  const int m0 = blockIdx.y * 128, n0 = blockIdx.x * 128;
  const unsigned short* Btz = Bt + (size_t)blockIdx.z * DMODEL * DMODEL;

  const int arow = t >> 2;
  const int csw = (t & 3) ^ ((t >> 3) & 3);
  const unsigned short* gA = A + (size_t)(m0 + arow) * DMODEL + csw * 8;
  const unsigned short* gB = Btz + (size_t)(n0 + arow) * DMODEL + csw * 8;
  unsigned short* lA0 = &As[t * 8];
  unsigned short* lA1 = &As[2048 + t * 8];
  unsigned short* lB0 = &Bs[t * 8];
  unsigned short* lB1 = &Bs[2048 + t * 8];

  const int sw = (lr >> 1) & 3;

  f32x4 acc[4][4];
  #pragma unroll
  for (int i = 0; i < 4; i++)
    #pragma unroll
    for (int j = 0; j < 4; j++) acc[i][j] = (f32x4){0.f, 0.f, 0.f, 0.f};

  for (int kt = 0; kt < DMODEL / 32; kt++) {
    GLOAD_LDS16(gA, lA0);
    GLOAD_LDS16(gA + (size_t)64 * DMODEL, lA1);
    GLOAD_LDS16(gB, lB0);
    GLOAD_LDS16(gB + (size_t)64 * DMODEL, lB1);
    gA += 32; gB += 32;
    __syncthreads();
    bf16x8 af[4], bfv[4];
    #pragma unroll
    for (int mt = 0; mt < 4; mt++)
      af[mt] = *(const bf16x8*)&As[(wm + mt * 16 + lr) * 32 + (quad ^ sw) * 8];
    #pragma unroll
    for (int nt = 0; nt < 4; nt++)
      bfv[nt] = *(const bf16x8*)&Bs[(wn + nt * 16 + lr) * 32 + (quad ^ sw) * 8];
    #pragma unroll
    for (int mt = 0; mt < 4; mt++)
      #pragma unroll
      for (int nt = 0; nt < 4; nt++)
        acc[mt][nt] = __builtin_amdgcn_mfma_f32_16x16x32_bf16(af[mt], bfv[nt], acc[mt][nt], 0, 0, 0);
    __syncthreads();
  }
  #pragma unroll
  for (int mt = 0; mt < 4; mt++) {
    #pragma unroll
    for (int r = 0; r < 4; r++) {
      int row = m0 + wm + mt * 16 + quad * 4 + r;
      if (row < M) {
        if (BF16OUT) {
          unsigned short* C = (unsigned short*)Cv + (size_t)blockIdx.z * c_stride_mat;
          #pragma unroll
          for (int nt = 0; nt < 4; nt++)
            C[(size_t)row * DMODEL + n0 + wn + nt * 16 + lr] = f2bf(acc[mt][nt][r]);
        } else {
          float* C = (float*)Cv + (size_t)blockIdx.z * c_stride_mat;
          #pragma unroll
          for (int nt = 0; nt < 4; nt++)
            C[(size_t)row * DMODEL + n0 + wn + nt * 16 + lr] = acc[mt][nt][r];
        }
      }
    }
  }
}

// ---------- 5. RoPE ----------
__global__ __launch_bounds__(256) void k_rope(const unsigned short* __restrict__ Qf,
                                              const unsigned short* __restrict__ Kf,
                                              const unsigned short* __restrict__ Vf,
                                              const float* __restrict__ cost, const float* __restrict__ sint,
                                              unsigned short* __restrict__ Qb, unsigned short* __restrict__ Kb,
                                              unsigned short* __restrict__ AKb, unsigned short* __restrict__ AVb) {
  int row = blockIdx.x;
  int t = threadIdx.x;
  int c0 = t * 8;
  size_t off = (size_t)row * DMODEL + c0;
  if (row < NB * SEQ) {
    int s = row & (SEQ - 1);
    int d0 = c0 & (HD - 1);
    int po = (d0 < 64) ? 64 : -64;
    float sign = (d0 < 64) ? -1.f : 1.f;
    uint4 qv = *(const uint4*)&Qf[off];
    uint4 qp = *(const uint4*)&Qf[off + po];
    uint4 kv = *(const uint4*)&Kf[off];
    uint4 kp = *(const uint4*)&Kf[off + po];
    const unsigned short* qa = (const unsigned short*)&qv;
    const unsigned short* qb2 = (const unsigned short*)&qp;
    const unsigned short* ka = (const unsigned short*)&kv;
    const unsigned short* kb2 = (const unsigned short*)&kp;
    unsigned short oq[8], ok[8];
    #pragma unroll
    for (int j = 0; j < 8; j++) {
      float cv = cost[s * HD + d0 + j], sv = sint[s * HD + d0 + j];
      oq[j] = f2bf(bf2f(qa[j]) * cv + sign * bf2f(qb2[j]) * sv);
      ok[j] = f2bf(bf2f(ka[j]) * cv + sign * bf2f(kb2[j]) * sv);
    }
    *(uint4*)&Qb[off] = *(const uint4*)oq;
    *(uint4*)&Kb[off] = *(const uint4*)ok;
  } else {
    int p = row - NB * SEQ;
    *(uint4*)&AKb[(size_t)p * DMODEL + c0] = *(const uint4*)&Kf[off];
    *(uint4*)&AVb[(size_t)p * DMODEL + c0] = *(const uint4*)&Vf[off];
  }
}

// ---------- 6. V transpose via LDS ----------
__global__ __launch_bounds__(256) void k_vt(const unsigned short* __restrict__ Vf,
                                            unsigned short* __restrict__ Vt) {
  __shared__ unsigned short tile[64][72];
  const int t = threadIdx.x;
  int s0 = blockIdx.x * 64;
  int d0 = blockIdx.y * 64;
  int b = blockIdx.z >> 4, h = blockIdx.z & 15;
  #pragma unroll
  for (int j = t; j < 512; j += 256) {
    int row = j >> 3, ch = j & 7;
    *(uint4*)&tile[row][ch * 8] =
      *(const uint4*)&Vf[(size_t)(b * SEQ + s0 + row) * DMODEL + h * HD + d0 + ch * 8];
  }
  __syncthreads();
  #pragma unroll
  for (int j = t; j < 512; j += 256) {
    int dr = j >> 3, ch = j & 7;
    unsigned short tmp[8];
    #pragma unroll
    for (int k = 0; k < 8; k++) tmp[k] = tile[ch * 8 + k][dr];
    *(uint4*)&Vt[((size_t)((b * NH + h) * HD + d0 + dr)) * SEQ + s0 + ch * 8] = *(const uint4*)tmp;
  }
}

// ---------- 7. flash attention, split-K + fused adapter ----------
// x-slot map (xm = blockIdx.x>>4): [0,8): split chunk A of qt=15-xm (+adapter);
// [8,16): split chunk B of qt=23-xm; [16,24): whole qt=xm-16.
// Co-resident triples {xm, xm+8, xm+16} each total exactly 34 k-iterations.
#define PSTR 68

__global__ __launch_bounds__(256, 3) void k_flash(const unsigned short* __restrict__ Qb,
                                               const unsigned short* __restrict__ Kb,
                                               const unsigned short* __restrict__ Vt,
                                               const unsigned short* __restrict__ AKb,
                                               const unsigned short* __restrict__ AVb,
                                               const float* __restrict__ gate,
                                               unsigned short* __restrict__ Out,
                                               unsigned short* __restrict__ Obuf,
                                               float* __restrict__ ml,
                                               unsigned short* __restrict__ Aout) {
  const int L = blockIdx.x;          // 0..383; h in low bits -> head-clustered per XCD
  const int h = L & 15;
  const int xm = L >> 4;
  const int b = blockIdx.y;
  int qt, kt0, kt1, mode;            // 0=whole, 1=splitA, 2=splitB
  if (xm < 8)       { qt = 15 - xm; kt0 = 0;      kt1 = qt + 1;     mode = 1; }
  else if (xm < 16) { qt = 23 - xm; kt0 = qt + 1; kt1 = 2 * qt + 2; mode = 2; }
  else              { qt = xm - 16; kt0 = 0;      kt1 = 2 * qt + 2; mode = 0; }

  const int t = threadIdx.x, w = t >> 6, lane = t & 63;
  const int lr = lane & 15, quad = lane >> 4;

  __shared__ unsigned short Ks[64 * 128];
  __shared__ unsigned short Vs[128 * 64];
  __shared__ unsigned short Ps[4][32 * PSTR];

  const int row_base = qt * 128 + w * 32;

  bf16x8 qf[2][4];
  #pragma unroll
  for (int mt = 0; mt < 2; mt++)
    #pragma unroll
    for (int kk = 0; kk < 4; kk++)
      qf[mt][kk] = *(const bf16x8*)&Qb[((size_t)(b * SEQ + row_base + mt * 16 + lr)) * DMODEL
                                       + h * HD + kk * 32 + quad * 8];

  f32x4 o[2][8];
  #pragma unroll
  for (int mt = 0; mt < 2; mt++)
    #pragma unroll
    for (int nt = 0; nt < 8; nt++) o[mt][nt] = (f32x4){0.f, 0.f, 0.f, 0.f};
  float m_i[2][4], l_i[2][4];
  #pragma unroll
  for (int mt = 0; mt < 2; mt++)
    #pragma unroll
    for (int r = 0; r < 4; r++) { m_i[mt][r] = -__builtin_inff(); l_i[mt][r] = 0.f; }

  const int krow = t >> 4;
  const int vd = t >> 3, vc = (t & 7) ^ (vd & 7);

  for (int kt = kt0; kt < kt1; kt++) {
    __syncthreads();
    #pragma unroll
    for (int j = 0; j < 4; j++) {
      int row = krow + j * 16;
      int c = (t & 15) ^ (row & 15);
      GLOAD_LDS16(&Kb[((size_t)(b * SEQ + kt * 64 + row)) * DMODEL + h * HD + c * 8],
                  &Ks[(t + j * 256) * 8]);
    }
    #pragma unroll
    for (int j = 0; j < 4; j++) {
      int d = vd + j * 32;
      GLOAD_LDS16(&Vt[((size_t)((b * NH + h) * HD + d)) * SEQ + kt * 64 + vc * 8],
                  &Vs[(t + j * 256) * 8]);
    }
    __syncthreads();

    f32x4 s4[2][4];
    #pragma unroll
    for (int mt = 0; mt < 2; mt++)
      #pragma unroll
      for (int nt = 0; nt < 4; nt++) s4[mt][nt] = (f32x4){0.f, 0.f, 0.f, 0.f};
    #pragma unroll
    for (int nt = 0; nt < 4; nt++)
      #pragma unroll
      for (int kk = 0; kk < 4; kk++) {
        bf16x8 bv = *(const bf16x8*)&Ks[((nt * 16 + lr) * 16 + ((kk * 4 + quad) ^ lr)) * 8];
        s4[0][nt] = __builtin_amdgcn_mfma_f32_16x16x32_bf16(qf[0][kk], bv, s4[0][nt], 0, 0, 0);
        s4[1][nt] = __builtin_amdgcn_mfma_f32_16x16x32_bf16(qf[1][kk], bv, s4[1][nt], 0, 0, 0);
      }

    const int maybe_mask = (kt * 64 + 63 > row_base);
    #pragma unroll
    for (int mt = 0; mt < 2; mt++) {
      #pragma unroll
      for (int nt = 0; nt < 4; nt++) s4[mt][nt] = s4[mt][nt] * SCALEL2;
      if (maybe_mask) {
        #pragma unroll
        for (int nt = 0; nt < 4; nt++) {
          int col = kt * 64 + nt * 16 + lr;
          #pragma unroll
          for (int r = 0; r < 4; r++)
            if (col > row_base + mt * 16 + quad * 4 + r) s4[mt][nt][r] = -__builtin_inff();
        }
      }
      #pragma unroll
      for (int r = 0; r < 4; r++) {
        float tm = fmaxf(fmaxf(s4[mt][0][r], s4[mt][1][r]), fmaxf(s4[mt][2][r], s4[mt][3][r]));
        #pragma unroll
        for (int off = 1; off < 16; off <<= 1) tm = fmaxf(tm, __shfl_xor(tm, off, 64));
        float mnew = fmaxf(m_i[mt][r], tm);
        float p0 = __builtin_amdgcn_exp2f(s4[mt][0][r] - mnew);
        float p1 = __builtin_amdgcn_exp2f(s4[mt][1][r] - mnew);
        float p2 = __builtin_amdgcn_exp2f(s4[mt][2][r] - mnew);
        float p3 = __builtin_amdgcn_exp2f(s4[mt][3][r] - mnew);
        s4[mt][0][r] = p0; s4[mt][1][r] = p1; s4[mt][2][r] = p2; s4[mt][3][r] = p3;
        float alpha = __builtin_amdgcn_exp2f(m_i[mt][r] - mnew);
        l_i[mt][r] = alpha * l_i[mt][r] + (p0 + p1) + (p2 + p3);
        m_i[mt][r] = mnew;
        #pragma unroll
        for (int nt = 0; nt < 8; nt++) o[mt][nt][r] *= alpha;
      }
      #pragma unroll
      for (int nt = 0; nt < 4; nt++)
        #pragma unroll
        for (int r = 0; r < 4; r++)
          Ps[w][(mt * 16 + quad * 4 + r) * PSTR + nt * 16 + lr] = f2bf(s4[mt][nt][r]);
    }
    #pragma unroll
    for (int kk2 = 0; kk2 < 2; kk2++) {
      bf16x8 af0 = *(const bf16x8*)&Ps[w][(lr) * PSTR + kk2 * 32 + quad * 8];
      bf16x8 af1 = *(const bf16x8*)&Ps[w][(16 + lr) * PSTR + kk2 * 32 + quad * 8];
      #pragma unroll
      for (int nt = 0; nt < 8; nt++) {
        bf16x8 bv = *(const bf16x8*)&Vs[((nt * 16 + lr) * 8 + ((kk2 * 4 + quad) ^ (lr & 7))) * 8];
        o[0][nt] = __builtin_amdgcn_mfma_f32_16x16x32_bf16(af0, bv, o[0][nt], 0, 0, 0);
        o[1][nt] = __builtin_amdgcn_mfma_f32_16x16x32_bf16(af1, bv, o[1][nt], 0, 0, 0);
      }
    }
  }

  // reduce deferred row-sums
  #pragma unroll
  for (int mt = 0; mt < 2; mt++)
    #pragma unroll
    for (int r = 0; r < 4; r++) {
      float l = l_i[mt][r];
      #pragma unroll
      for (int off = 1; off < 16; off <<= 1) l += __shfl_xor(l, off, 64);
      l_i[mt][r] = l;
    }

  if (mode == 2) {   // store partial 1, done
    size_t obase = (((size_t)NB + b) * NH + h) * 1024;   // part=1
    #pragma unroll
    for (int mt = 0; mt < 2; mt++)
      #pragma unroll
      for (int r = 0; r < 4; r++) {
        int rowlocal = qt * 128 - 1024 + w * 32 + mt * 16 + quad * 4 + r;
        #pragma unroll
        for (int nt = 0; nt < 8; nt++)
          Obuf[(obase + rowlocal) * 128 + nt * 16 + lr] = f2bf(o[mt][nt][r]);
        if (lr == 0) {
          ml[(obase + rowlocal) * 2] = m_i[mt][r];
          ml[(obase + rowlocal) * 2 + 1] = l_i[mt][r];
        }
      }
    return;
  }

  // ---- adapter (modes 0,1) ----
  __syncthreads();
  for (int i = t; i < 16 * 128; i += 256) {
    int p = i >> 7, d = i & 127;
    Ks[p * 128 + d] = (p < NP) ? AKb[(size_t)p * DMODEL + h * HD + d] : (unsigned short)0;
  }
  for (int i = t; i < 128 * 32; i += 256) {
    int d = i >> 5, p = i & 31;
    Vs[d * 32 + p] = (p < NP) ? AVb[(size_t)p * DMODEL + h * HD + d] : (unsigned short)0;
  }
  __syncthreads();

  const float g = gate[h];
  #pragma unroll
  for (int mt = 0; mt < 2; mt++) {
    f32x4 as4 = (f32x4){0.f, 0.f, 0.f, 0.f};
    #pragma unroll
    for (int kk = 0; kk < 4; kk++) {
      bf16x8 bv = *(const bf16x8*)&Ks[lr * 128 + kk * 32 + quad * 8];
      as4 = __builtin_amdgcn_mfma_f32_16x16x32_bf16(qf[mt][kk], bv, as4, 0, 0, 0);
    }
    as4 = as4 * SCALEL2;
    if (lr >= NP) {
      #pragma unroll
      for (int r = 0; r < 4; r++) as4[r] = -__builtin_inff();
    }
    float al[4];
    #pragma unroll
    for (int r = 0; r < 4; r++) {
      float tm = as4[r];
      #pragma unroll
      for (int off = 1; off < 16; off <<= 1) tm = fmaxf(tm, __shfl_xor(tm, off, 64));
      float p = __builtin_amdgcn_exp2f(as4[r] - tm);
      as4[r] = p;
      float sum = p;
      #pragma unroll
      for (int off = 1; off < 16; off <<= 1) sum += __shfl_xor(sum, off, 64);
      al[r] = sum;
    }
    #pragma unroll
    for (int r = 0; r < 4; r++) {
      Ps[w][(mt * 16 + quad * 4 + r) * PSTR + lr] = f2bf(as4[r]);
      Ps[w][(mt * 16 + quad * 4 + r) * PSTR + 16 + lr] = 0;
    }
    bf16x8 af = *(const bf16x8*)&Ps[w][(mt * 16 + lr) * PSTR + quad * 8];
    if (mode == 0) {
      float invl[4], invla[4];
      #pragma unroll
      for (int r = 0; r < 4; r++) { invl[r] = 1.0f / l_i[mt][r]; invla[r] = g / al[r]; }
      #pragma unroll
      for (int nt = 0; nt < 8; nt++) {
        bf16x8 bv = *(const bf16x8*)&Vs[(nt * 16 + lr) * 32 + quad * 8];
        f32x4 pa = __builtin_amdgcn_mfma_f32_16x16x32_bf16(af, bv, (f32x4){0.f, 0.f, 0.f, 0.f}, 0, 0, 0);
        #pragma unroll
        for (int r = 0; r < 4; r++) o[mt][nt][r] = o[mt][nt][r] * invl[r] + pa[r] * invla[r];
      }
      #pragma unroll
      for (int r = 0; r < 4; r++) {
        int srow = row_base + mt * 16 + quad * 4 + r;
        size_t base = ((size_t)(b * SEQ + srow)) * DMODEL + h * HD;
        #pragma unroll
        for (int nt = 0; nt < 8; nt++)
          Out[base + nt * 16 + lr] = f2bf(o[mt][nt][r]);
      }
    } else {   // mode 1: partial 0 + adapter term
      size_t obase = ((size_t)b * NH + h) * 1024;   // part=0
      float invla[4];
      #pragma unroll
      for (int r = 0; r < 4; r++) invla[r] = g / al[r];
      #pragma unroll
      for (int r = 0; r < 4; r++) {
        int rowlocal = qt * 128 - 1024 + w * 32 + mt * 16 + quad * 4 + r;
        if (lr == 0) {
          ml[(obase + rowlocal) * 2] = m_i[mt][r];
          ml[(obase + rowlocal) * 2 + 1] = l_i[mt][r];
        }
      }
      #pragma unroll
      for (int nt = 0; nt < 8; nt++) {
        bf16x8 bv = *(const bf16x8*)&Vs[(nt * 16 + lr) * 32 + quad * 8];
        f32x4 pa = __builtin_amdgcn_mfma_f32_16x16x32_bf16(af, bv, (f32x4){0.f, 0.f, 0.f, 0.f}, 0, 0, 0);
        #pragma unroll
        for (int r = 0; r < 4; r++) {
          int rowlocal = qt * 128 - 1024 + w * 32 + mt * 16 + quad * 4 + r;
          Obuf[(obase + rowlocal) * 128 + nt * 16 + lr] = f2bf(o[mt][nt][r]);
          Aout[(obase + rowlocal) * 128 + nt * 16 + lr] = f2bf(pa[r] * invla[r]);
        }
      }
    }
  }
}

// ---------- 8. merge split partials ----------
__global__ __launch_bounds__(256) void k_merge(const unsigned short* __restrict__ Obuf,
                                               const float* __restrict__ ml,
                                               const unsigned short* __restrict__ Aout,
                                               unsigned short* __restrict__ Out) {
  int idx = blockIdx.x * 256 + threadIdx.x;       // [0, 2*16*1024*16)
  int rowflat = idx >> 4;                          // (b,h,rl)
  int c8 = (idx & 15) * 8;
  int b = rowflat >> 14, h = (rowflat >> 10) & 15, rl = rowflat & 1023;
  size_t i0 = ((size_t)b * NH + h) * 1024 + rl;
  size_t i1 = (((size_t)NB + b) * NH + h) * 1024 + rl;
  float m0 = ml[i0 * 2], l0 = ml[i0 * 2 + 1];
  float m1 = ml[i1 * 2], l1 = ml[i1 * 2 + 1];
  float M = fmaxf(m0, m1);
  float e0 = __builtin_amdgcn_exp2f(m0 - M), e1 = __builtin_amdgcn_exp2f(m1 - M);
  float dn = 1.0f / (e0 * l0 + e1 * l1);
  uint4 o0 = *(const uint4*)&Obuf[i0 * 128 + c8];
  uint4 o1 = *(const uint4*)&Obuf[i1 * 128 + c8];
  uint4 av = *(const uint4*)&Aout[i0 * 128 + c8];
  const unsigned short* p0 = (const unsigned short*)&o0;
  const unsigned short* p1 = (const unsigned short*)&o1;
  const unsigned short* pa = (const unsigned short*)&av;
  unsigned short res[8];
  #pragma unroll
  for (int j = 0; j < 8; j++)
    res[j] = f2bf((e0 * bf2f(p0[j]) + e1 * bf2f(p1[j])) * dn + bf2f(pa[j]));
  *(uint4*)&Out[((size_t)(b * SEQ + 1024 + rl)) * DMODEL + h * HD + c8] = *(const uint4*)res;
}

// ---------- launcher ----------
extern "C" void kernel_launch(void* const* d_in, const int* in_sizes, int n_in,
                              void* d_out, int out_size, void* d_ws, size_t ws_size,
                              hipStream_t stream) {
  const float* hidden = (const float*)d_in[0];
  const float* Wq = (const float*)d_in[3];
  const float* Wk = (const float*)d_in[4];
  const float* Wv = (const float*)d_in[5];
  const float* Wo = (const float*)d_in[6];
  const float* Aq = (const float*)d_in[7];
  const float* gate = (const float*)d_in[8];
  float* out = (float*)d_out;

  char* ws = (char*)d_ws;
  size_t off = 0;
  auto alloc = [&](size_t bytes) -> void* {
    void* p = ws + off;
    off = (off + bytes + 255) & ~(size_t)255;
    return p;
  };
  unsigned short* wt   = (unsigned short*)alloc((size_t)4 * DMODEL * DMODEL * 2);
  unsigned short* xaug = (unsigned short*)alloc((size_t)MAUG * DMODEL * 2);
  unsigned short* qkvb = (unsigned short*)alloc((size_t)3 * MAUG * DMODEL * 2);
  unsigned short* qf = qkvb;
  unsigned short* kf = qkvb + (size_t)MAUG * DMODEL;
  unsigned short* vf = kf + (size_t)MAUG * DMODEL;
  unsigned short* qb  = (unsigned short*)alloc((size_t)NB * SEQ * DMODEL * 2);
  unsigned short* kb  = (unsigned short*)alloc((size_t)NB * SEQ * DMODEL * 2);
  unsigned short* vt  = (unsigned short*)alloc((size_t)NB * SEQ * DMODEL * 2);
  unsigned short* akb = (unsigned short*)alloc((size_t)NP * DMODEL * 2);
  unsigned short* avb = (unsigned short*)alloc((size_t)NP * DMODEL * 2);
  float* cost = (float*)alloc((size_t)SEQ * HD * 4);
  float* sint = (float*)alloc((size_t)SEQ * HD * 4);
  unsigned short* obuf = (unsigned short*)alloc((size_t)2 * NB * NH * 1024 * 128 * 2);
  float* mlb = (float*)alloc((size_t)2 * NB * NH * 1024 * 2 * 4);
  unsigned short* aout = (unsigned short*)alloc((size_t)NB * NH * 1024 * 128 * 2);
  unsigned short* ab = qf;   // reuse: qf dead after k_rope

  k_tables<<<SEQ * 64 / 256, 256, 0, stream>>>(cost, sint);
  k_wt<<<dim3(64, 64, 4), 256, 0, stream>>>(Wq, Wk, Wv, Wo, wt);
  {
    size_t n = (size_t)MAUG * DMODEL;
    k_xaug<<<(unsigned)((n + 255) / 256), 256, 0, stream>>>(hidden, Aq, xaug);
  }
  k_gemm<1><<<dim3(16, 33, 3), 256, 0, stream>>>(xaug, wt, qkvb, MAUG, (size_t)MAUG * DMODEL);
  k_rope<<<MAUG, 256, 0, stream>>>(qf, kf, vf, cost, sint, qb, kb, akb, avb);
  k_vt<<<dim3(32, 2, 32), 256, 0, stream>>>(vf, vt);
  k_flash<<<dim3(384, 2), 256, 0, stream>>>(qb, kb, vt, akb, avb, gate, ab, obuf, mlb, aout);
  k_merge<<<2048, 256, 0, stream>>>(obuf, mlb, aout, ab);
  k_gemm<0><<<dim3(16, 32, 1), 256, 0, stream>>>(ab, wt + (size_t)3 * DMODEL * DMODEL, out, NB * SEQ, 0);
}